// Round 3
// baseline (553.013 us; speedup 1.0000x reference)
//
#include <hip/hip_runtime.h>
#include <hip/hip_bf16.h>
#include <math.h>

// Problem constants
#define B_   512
#define NS_  2
#define S_   128
#define H_   768
#define DS_  384
#define NL_  40
#define H3_  (3*H_)      // 2304
#define TEMP_ 0.05f
#define ALPHA_ 0.15f
#define GAMMA_ 7.5f
#define EPS_ 1e-8f

typedef __attribute__((ext_vector_type(8))) short bf8_t;
typedef __attribute__((ext_vector_type(4))) short s4_t;
typedef __attribute__((ext_vector_type(4))) float f4_t;

#define LDSPAD 40   // bf16 row stride for 32-wide k tiles (80B, 16B-aligned)

// ---------------- helpers ----------------

__device__ __forceinline__ short bfbits(float x) {
    __hip_bfloat16 h = __float2bfloat16(x);
    return *reinterpret_cast<short*>(&h);
}

// blockDim == 256 (4 waves). Wave shuffle reduce + 2 barriers.
__device__ __forceinline__ float block_reduce_sum(float v, float* sh) {
#pragma unroll
    for (int off = 32; off >= 1; off >>= 1) v += __shfl_down(v, off, 64);
    int w = threadIdx.x >> 6;
    if ((threadIdx.x & 63) == 0) sh[w] = v;
    __syncthreads();
    float r = (sh[0] + sh[1]) + (sh[2] + sh[3]);
    __syncthreads();
    return r;
}

__device__ __forceinline__ float block_reduce_max(float v, float* sh) {
#pragma unroll
    for (int off = 32; off >= 1; off >>= 1) v = fmaxf(v, __shfl_down(v, off, 64));
    int w = threadIdx.x >> 6;
    if ((threadIdx.x & 63) == 0) sh[w] = v;
    __syncthreads();
    float r = fmaxf(fmaxf(sh[0], sh[1]), fmaxf(sh[2], sh[3]));
    __syncthreads();
    return r;
}

// ---------------- kernel 1: prep ----------------
__device__ __forceinline__ void transpose_tile(
    const float* __restrict__ in, __hip_bfloat16* __restrict__ out,
    int K, int N, int kt, int nt, int tid, float* tileLds /* 32*33 */)
{
    int k0 = kt * 32, n0 = nt * 32;
    int tx = tid & 31, ty = tid >> 5;   // ty 0..7
#pragma unroll
    for (int i = 0; i < 4; ++i) {
        int k = k0 + ty + i * 8, n = n0 + tx;
        if (k < K && n < N) tileLds[(ty + i*8) * 33 + tx] = in[(size_t)k * N + n];
    }
    __syncthreads();
#pragma unroll
    for (int i = 0; i < 4; ++i) {
        int n = n0 + ty + i * 8, k = k0 + tx;
        if (n < N && k < K) out[(size_t)n * K + k] = __float2bfloat16(tileLds[tx * 33 + ty + i*8]);
    }
}

__global__ __launch_bounds__(256) void prep_kernel(
    const float* __restrict__ bert, const int* __restrict__ eidx,
    const float* __restrict__ dense_w, const float* __restrict__ fc_w,
    const float* __restrict__ cls_w, const float* __restrict__ desc,
    __hip_bfloat16* __restrict__ rh_bf, __hip_bfloat16* __restrict__ toks_bf,
    __hip_bfloat16* __restrict__ dwt, __hip_bfloat16* __restrict__ fwt,
    __hip_bfloat16* __restrict__ cwt, __hip_bfloat16* __restrict__ desc_nb,
    float* __restrict__ tok_ss, float* __restrict__ acc, int* __restrict__ done)
{
    __shared__ float tileLds[32 * 33];
    int blk = blockIdx.x;
    int t = threadIdx.x;
    if (blk < 512) {
        int b = blk;
        if (b == 0) {
            if (t < 4) acc[t] = 0.0f;
            if (t == 4) *done = 0;
        }
        if (b == 1) {   // zero tok_ss (2048 floats)
            for (int i = t; i < 4 * B_; i += 256) tok_ss[i] = 0.0f;
        }
        int e00 = eidx[b*4 + 0];
        int e01 = eidx[b*4 + 1];
        int e10 = eidx[b*4 + 2];
        int e11 = eidx[b*4 + 3];
        const float* s0 = bert + (size_t)b * NS_ * S_ * H_;
        const float* s1 = s0 + (size_t)S_ * H_;
        const float* cls  = s0;
        const float* head = s0 + (size_t)e00 * H_;
        const float* tail = s0 + (size_t)e01 * H_;
        const float* h2a  = s1 + (size_t)e10 * H_;
        const float* h2b  = s1 + (size_t)e11 * H_;
        __hip_bfloat16* rhb = rh_bf + (size_t)b * H3_;
        __hip_bfloat16* tk  = toks_bf + (size_t)b * 4 * H_;
        for (int h = t; h < H_; h += 256) {
            float c  = cls[h];
            float hd = head[h];
            float tl = tail[h];
            rhb[h]        = __float2bfloat16(tanhf(c));
            rhb[H_ + h]   = __float2bfloat16(tanhf(hd));
            rhb[2*H_ + h] = __float2bfloat16(tanhf(tl));
            tk[h]         = __float2bfloat16(hd);
            tk[H_ + h]    = __float2bfloat16(tl);
            tk[2*H_ + h]  = __float2bfloat16(h2a[h]);
            tk[3*H_ + h]  = __float2bfloat16(h2b[h]);
        }
    } else if (blk < 1088) {
        int q = blk - 512;          // 24x24 tiles
        transpose_tile(dense_w, dwt, H_, H_, q / 24, q % 24, t, tileLds);
    } else if (blk < 1952) {
        int q = blk - 1088;         // 72x12 tiles
        transpose_tile(fc_w, fwt, H3_, DS_, q / 12, q % 12, t, tileLds);
    } else if (blk < 2096) {
        int q = blk - 1952;         // 72x2 tiles
        int kt = q / 2, nt = q % 2;
        transpose_tile(cls_w, cwt, H3_, NL_, kt, nt, t, tileLds);
        if (nt == 1) {              // zero pad rows 40..47 for this k-range
            int tx = t & 31, ty = t >> 5;
            cwt[(size_t)(40 + ty) * H3_ + kt * 32 + tx] = __float2bfloat16(0.0f);
        }
    } else {
        int i = blk - 2096;         // desc norm, D=384
        const float* x = desc + (size_t)i * DS_;
        float ss = 0.0f;
        for (int d = t; d < DS_; d += 256) { float v = x[d]; ss += v * v; }
        ss = block_reduce_sum(ss, tileLds);
        float inv = 1.0f / fmaxf(sqrtf(ss), EPS_);
        __hip_bfloat16* o = desc_nb + (size_t)i * DS_;
        for (int d = t; d < DS_; d += 256) o[d] = __float2bfloat16(x[d] * inv);
    }
}

// ---------------- dense 128x128 body: Z = bf16(tanh(A@B^T + bias)), row sumsq -> tok_ss ----------------
__device__ __forceinline__ void dense128_body(
    const __hip_bfloat16* __restrict__ A, const __hip_bfloat16* __restrict__ Bp,
    const float* __restrict__ bias, __hip_bfloat16* __restrict__ Z,
    float* __restrict__ tok_ss, int bx, int by,
    __hip_bfloat16* As0, __hip_bfloat16* Bs0,
    __hip_bfloat16* As1, __hip_bfloat16* Bs1)
{
    int tid  = threadIdx.x;
    int lane = tid & 63;
    int wave = tid >> 6;
    int wm = (wave >> 1) * 64;
    int wn = (wave & 1) * 64;
    int lr = lane & 15;
    int quad = lane >> 4;
    int rowBase = by * 128;
    int colBase = bx * 128;

    f4_t acc[4][4];
#pragma unroll
    for (int i = 0; i < 4; ++i)
#pragma unroll
        for (int j = 0; j < 4; ++j) acc[i][j] = (f4_t){0.f, 0.f, 0.f, 0.f};

    int sr = tid >> 2, sc = tid & 3;
    const __hip_bfloat16* Abase = A + (size_t)(rowBase + sr) * H_ + sc * 8;
    const __hip_bfloat16* Bbase = Bp + (size_t)(colBase + sr) * H_ + sc * 8;
    size_t a64 = (size_t)64 * H_;

    *(bf8_t*)&As0[sr * LDSPAD + sc * 8]        = *(const bf8_t*)(Abase);
    *(bf8_t*)&As0[(sr + 64) * LDSPAD + sc * 8] = *(const bf8_t*)(Abase + a64);
    *(bf8_t*)&Bs0[sr * LDSPAD + sc * 8]        = *(const bf8_t*)(Bbase);
    *(bf8_t*)&Bs0[(sr + 64) * LDSPAD + sc * 8] = *(const bf8_t*)(Bbase + a64);
    __syncthreads();

    const int nIter = H_ >> 5;   // 24
    for (int i = 0; i < nIter; ++i) {
        __hip_bfloat16* Asc = (i & 1) ? As1 : As0;
        __hip_bfloat16* Bsc = (i & 1) ? Bs1 : Bs0;
        __hip_bfloat16* Asn = (i & 1) ? As0 : As1;
        __hip_bfloat16* Bsn = (i & 1) ? Bs0 : Bs1;
        bf8_t pa0, pa1, pb0, pb1;
        bool pf = (i + 1 < nIter);
        if (pf) {
            int k = (i + 1) << 5;
            pa0 = *(const bf8_t*)(Abase + k);
            pa1 = *(const bf8_t*)(Abase + a64 + k);
            pb0 = *(const bf8_t*)(Bbase + k);
            pb1 = *(const bf8_t*)(Bbase + a64 + k);
        }
        bf8_t af[4], bfr[4];
#pragma unroll
        for (int f = 0; f < 4; ++f) {
            af[f]  = *(const bf8_t*)&Asc[(wm + f*16 + lr) * LDSPAD + quad * 8];
            bfr[f] = *(const bf8_t*)&Bsc[(wn + f*16 + lr) * LDSPAD + quad * 8];
        }
#pragma unroll
        for (int ii = 0; ii < 4; ++ii)
#pragma unroll
            for (int j = 0; j < 4; ++j)
                acc[ii][j] = __builtin_amdgcn_mfma_f32_16x16x32_bf16(af[ii], bfr[j], acc[ii][j], 0, 0, 0);
        if (pf) {
            *(bf8_t*)&Asn[sr * LDSPAD + sc * 8]        = pa0;
            *(bf8_t*)&Asn[(sr + 64) * LDSPAD + sc * 8] = pa1;
            *(bf8_t*)&Bsn[sr * LDSPAD + sc * 8]        = pb0;
            *(bf8_t*)&Bsn[(sr + 64) * LDSPAD + sc * 8] = pb1;
        }
        __syncthreads();
    }

    // epilogue: tanh -> bf16 store + per-row sum-of-squares (f32, pre-rounding)
    float bv[4];
#pragma unroll
    for (int j = 0; j < 4; ++j) bv[j] = bias[colBase + wn + j*16 + lr];
    float* rowp = (float*)As0;      // LDS free after final barrier; 128*33*4 = 16.9 KB
    int wnOff = wn ? 16 : 0;
#pragma unroll
    for (int i = 0; i < 4; ++i) {
#pragma unroll
        for (int r = 0; r < 4; ++r) {
            int rowL = wm + i*16 + quad*4 + r;      // 0..127
            float p = 0.0f;
#pragma unroll
            for (int j = 0; j < 4; ++j) {
                float v = tanhf(acc[i][j][r] + bv[j]);
                Z[(size_t)(rowBase + rowL) * H_ + colBase + wn + j*16 + lr] = __float2bfloat16(v);
                p += v * v;
            }
            rowp[rowL * 33 + wnOff + lr] = p;
        }
    }
    __syncthreads();
    if (tid < 128) {
        float s = 0.0f;
#pragma unroll
        for (int k = 0; k < 32; ++k) s += rowp[tid * 33 + k];
        atomicAdd(tok_ss + rowBase + tid, s);
    }
}

// ---------------- 64x64 body (fc partials / C2-with-norm) ----------------
// C = scale * (A[:,kBase:kBase+K] @ B[:,kBase:kBase+K]^T); if tok_ss != null,
// additionally scale by 1/(||z1_row|| * ||z2_col||)  (z sumsq from tok_ss).
__device__ __forceinline__ void gemm64_body(
    const __hip_bfloat16* __restrict__ A, const __hip_bfloat16* __restrict__ Bp,
    float* __restrict__ C, const float* __restrict__ tok_ss,
    int K, int kBase, int lda, int ldb, int ldc, float scale, int bx, int by,
    __hip_bfloat16* As0, __hip_bfloat16* Bs0,
    __hip_bfloat16* As1, __hip_bfloat16* Bs1)
{
    int tid  = threadIdx.x;
    int lane = tid & 63;
    int wave = tid >> 6;
    int lr = lane & 15;
    int quad = lane >> 4;
    int rowBase = by * 64;
    int colBase = bx * 64;

    f4_t acc[4];
#pragma unroll
    for (int i = 0; i < 4; ++i) acc[i] = (f4_t){0.f, 0.f, 0.f, 0.f};

    int sr = tid >> 2, sc = tid & 3;
    const __hip_bfloat16* Abase = A + (size_t)(rowBase + sr) * lda + kBase + sc * 8;
    const __hip_bfloat16* Bbase = Bp + (size_t)(colBase + sr) * ldb + kBase + sc * 8;

    *(bf8_t*)&As0[sr * LDSPAD + sc * 8] = *(const bf8_t*)(Abase);
    *(bf8_t*)&Bs0[sr * LDSPAD + sc * 8] = *(const bf8_t*)(Bbase);
    __syncthreads();

    int nIter = K >> 5;
    for (int i = 0; i < nIter; ++i) {
        __hip_bfloat16* Asc = (i & 1) ? As1 : As0;
        __hip_bfloat16* Bsc = (i & 1) ? Bs1 : Bs0;
        __hip_bfloat16* Asn = (i & 1) ? As0 : As1;
        __hip_bfloat16* Bsn = (i & 1) ? Bs0 : Bs1;
        bf8_t pa, pb;
        bool pf = (i + 1 < nIter);
        if (pf) {
            int k = (i + 1) << 5;
            pa = *(const bf8_t*)(Abase + k);
            pb = *(const bf8_t*)(Bbase + k);
        }
        bf8_t bfr = *(const bf8_t*)&Bsc[(wave*16 + lr) * LDSPAD + quad * 8];
#pragma unroll
        for (int f = 0; f < 4; ++f) {
            bf8_t af = *(const bf8_t*)&Asc[(f*16 + lr) * LDSPAD + quad * 8];
            acc[f] = __builtin_amdgcn_mfma_f32_16x16x32_bf16(af, bfr, acc[f], 0, 0, 0);
        }
        if (pf) {
            *(bf8_t*)&Asn[sr * LDSPAD + sc * 8] = pa;
            *(bf8_t*)&Bsn[sr * LDSPAD + sc * 8] = pb;
        }
        __syncthreads();
    }
    int col = colBase + wave*16 + lr;
    float cinv = 1.0f;
    if (tok_ss) cinv = 1.0f / fmaxf(sqrtf(tok_ss[4*col + 2] + tok_ss[4*col + 3]), EPS_);
#pragma unroll
    for (int f = 0; f < 4; ++f) {
#pragma unroll
        for (int r = 0; r < 4; ++r) {
            int row = rowBase + f*16 + quad*4 + r;
            float v = acc[f][r] * scale * cinv;
            if (tok_ss) v *= 1.0f / fmaxf(sqrtf(tok_ss[4*row] + tok_ss[4*row + 1]), EPS_);
            C[(size_t)row * ldc + col] = v;
        }
    }
}

// ---------------- C1 body: combine fc partials + bias, norm rows in-block ----------------
// C1[i][j] = (bf16(relP0+relP1+fc_b)_i . descN_j) / max(||rel_i||, EPS)
__device__ __forceinline__ void c1_body(
    const float* __restrict__ relP0, const float* __restrict__ relP1,
    const float* __restrict__ fc_b, const __hip_bfloat16* __restrict__ descN,
    float* __restrict__ C1, int bx, int by,
    __hip_bfloat16* As0, __hip_bfloat16* Bs0,
    __hip_bfloat16* As1, __hip_bfloat16* Bs1, float* rssLds /* 64*4 */)
{
    int tid  = threadIdx.x;
    int lane = tid & 63;
    int wave = tid >> 6;
    int lr = lane & 15;
    int quad = lane >> 4;
    int rowBase = by * 64;
    int colBase = bx * 64;

    f4_t acc[4];
#pragma unroll
    for (int i = 0; i < 4; ++i) acc[i] = (f4_t){0.f, 0.f, 0.f, 0.f};

    int sr = tid >> 2, sc = tid & 3;
    const float* p0 = relP0 + (size_t)(rowBase + sr) * DS_ + sc * 8;
    const float* p1 = relP1 + (size_t)(rowBase + sr) * DS_ + sc * 8;
    const float* bb = fc_b + sc * 8;
    const __hip_bfloat16* Bbase = descN + (size_t)(colBase + sr) * DS_ + sc * 8;
    float rss = 0.0f;

    // initial stage (k = 0)
    {
        f4_t u0 = *(const f4_t*)(p0);     f4_t u1 = *(const f4_t*)(p0 + 4);
        f4_t w0 = *(const f4_t*)(p1);     f4_t w1 = *(const f4_t*)(p1 + 4);
        f4_t b0 = *(const f4_t*)(bb);     f4_t b1 = *(const f4_t*)(bb + 4);
        u0 += w0 + b0; u1 += w1 + b1;
        rss += u0[0]*u0[0] + u0[1]*u0[1] + u0[2]*u0[2] + u0[3]*u0[3]
             + u1[0]*u1[0] + u1[1]*u1[1] + u1[2]*u1[2] + u1[3]*u1[3];
        s4_t o0 = { bfbits(u0[0]), bfbits(u0[1]), bfbits(u0[2]), bfbits(u0[3]) };
        s4_t o1 = { bfbits(u1[0]), bfbits(u1[1]), bfbits(u1[2]), bfbits(u1[3]) };
        *(s4_t*)&As0[sr * LDSPAD + sc * 8]     = o0;
        *(s4_t*)&As0[sr * LDSPAD + sc * 8 + 4] = o1;
        *(bf8_t*)&Bs0[sr * LDSPAD + sc * 8] = *(const bf8_t*)(Bbase);
    }
    __syncthreads();

    const int nIter = DS_ >> 5;   // 12
    for (int i = 0; i < nIter; ++i) {
        __hip_bfloat16* Asc = (i & 1) ? As1 : As0;
        __hip_bfloat16* Bsc = (i & 1) ? Bs1 : Bs0;
        __hip_bfloat16* Asn = (i & 1) ? As0 : As1;
        __hip_bfloat16* Bsn = (i & 1) ? Bs0 : Bs1;
        bool pf = (i + 1 < nIter);
        f4_t u0, u1, w0, w1, b0, b1; bf8_t pb;
        if (pf) {
            int k = (i + 1) << 5;
            u0 = *(const f4_t*)(p0 + k);     u1 = *(const f4_t*)(p0 + k + 4);
            w0 = *(const f4_t*)(p1 + k);     w1 = *(const f4_t*)(p1 + k + 4);
            b0 = *(const f4_t*)(bb + k);     b1 = *(const f4_t*)(bb + k + 4);
            pb = *(const bf8_t*)(Bbase + k);
        }
        bf8_t bfr = *(const bf8_t*)&Bsc[(wave*16 + lr) * LDSPAD + quad * 8];
#pragma unroll
        for (int f = 0; f < 4; ++f) {
            bf8_t af = *(const bf8_t*)&Asc[(f*16 + lr) * LDSPAD + quad * 8];
            acc[f] = __builtin_amdgcn_mfma_f32_16x16x32_bf16(af, bfr, acc[f], 0, 0, 0);
        }
        if (pf) {
            u0 += w0 + b0; u1 += w1 + b1;
            rss += u0[0]*u0[0] + u0[1]*u0[1] + u0[2]*u0[2] + u0[3]*u0[3]
                 + u1[0]*u1[0] + u1[1]*u1[1] + u1[2]*u1[2] + u1[3]*u1[3];
            s4_t o0 = { bfbits(u0[0]), bfbits(u0[1]), bfbits(u0[2]), bfbits(u0[3]) };
            s4_t o1 = { bfbits(u1[0]), bfbits(u1[1]), bfbits(u1[2]), bfbits(u1[3]) };
            *(s4_t*)&Asn[sr * LDSPAD + sc * 8]     = o0;
            *(s4_t*)&Asn[sr * LDSPAD + sc * 8 + 4] = o1;
            *(bf8_t*)&Bsn[sr * LDSPAD + sc * 8] = pb;
        }
        __syncthreads();
    }

    rssLds[sr * 4 + sc] = rss;
    __syncthreads();
    int col = colBase + wave*16 + lr;
#pragma unroll
    for (int f = 0; f < 4; ++f) {
#pragma unroll
        for (int r = 0; r < 4; ++r) {
            int rowL = f*16 + quad*4 + r;
            float ss = rssLds[rowL*4] + rssLds[rowL*4+1] + rssLds[rowL*4+2] + rssLds[rowL*4+3];
            float inv = 1.0f / fmaxf(sqrtf(ss), EPS_);
            C1[(size_t)(rowBase + rowL) * B_ + col] = acc[f][r] * inv;
        }
    }
}

// cls logits + CE, 16 rows/block, K split across 4 waves, no LDS staging.
__device__ __forceinline__ void cls_ce_body(
    const __hip_bfloat16* __restrict__ rh, const __hip_bfloat16* __restrict__ cwt,
    const float* __restrict__ cls_b, const int* __restrict__ labels,
    float* __restrict__ acc, int rowBase, float* lgp /* 4*16*48 floats */)
{
    int tid  = threadIdx.x;
    int lane = tid & 63;
    int wave = tid >> 6;
    int lr = lane & 15;
    int quad = lane >> 4;

    f4_t a3[3];
#pragma unroll
    for (int j = 0; j < 3; ++j) a3[j] = (f4_t){0.f, 0.f, 0.f, 0.f};

    int kw0 = wave * (H3_ / 4);    // 576 per wave
    const __hip_bfloat16* aRow = rh + (size_t)(rowBase + lr) * H3_ + quad * 8;
#pragma unroll 2
    for (int s = 0; s < 18; ++s) {
        int k = kw0 + s * 32;
        bf8_t af = *(const bf8_t*)(aRow + k);
#pragma unroll
        for (int j = 0; j < 3; ++j) {
            bf8_t bfr = *(const bf8_t*)(cwt + (size_t)(j*16 + lr) * H3_ + k + quad * 8);
            a3[j] = __builtin_amdgcn_mfma_f32_16x16x32_bf16(af, bfr, a3[j], 0, 0, 0);
        }
    }
#pragma unroll
    for (int j = 0; j < 3; ++j) {
        int col = j*16 + lr;
#pragma unroll
        for (int r = 0; r < 4; ++r)
            lgp[wave * 768 + (quad*4 + r) * 48 + col] = a3[j][r];
    }
    __syncthreads();
    for (int idx = tid; idx < 768; idx += 256) {
        int col = idx % 48;
        float s = lgp[idx] + lgp[768 + idx] + lgp[1536 + idx] + lgp[2304 + idx];
        s = (col < NL_) ? (s + cls_b[col]) : -INFINITY;
        lgp[idx] = s;
    }
    __syncthreads();
    if (tid < 64) {
        float ce = 0.0f;
        if (tid < 16) {
            const float* Lr = &lgp[tid * 48];
            float m = -INFINITY;
            for (int c = 0; c < NL_; ++c) m = fmaxf(m, Lr[c]);
            float s = 0.0f;
            for (int c = 0; c < NL_; ++c) s += expf(Lr[c] - m);
            ce = logf(s) + m - Lr[labels[rowBase + tid]];
        }
        for (int off = 8; off >= 1; off >>= 1) ce += __shfl_down(ce, off);
        if (tid == 0) atomicAdd(acc + 0, ce * (1.0f / (float)B_));
    }
}

// ---------------- kernel 2: dense(96) + fc split-K(96) + cls_ce(32) = 224 blocks ----------------
__global__ __launch_bounds__(256) void gemms_kernel(
    const __hip_bfloat16* __restrict__ toks_bf, const __hip_bfloat16* __restrict__ dwt,
    const float* __restrict__ dense_b, __hip_bfloat16* __restrict__ z_bf,
    float* __restrict__ tok_ss,
    const __hip_bfloat16* __restrict__ rh_bf, const __hip_bfloat16* __restrict__ fwt,
    float* __restrict__ relP0, float* __restrict__ relP1,
    const __hip_bfloat16* __restrict__ cwt, const float* __restrict__ cls_b,
    const int* __restrict__ labels, float* __restrict__ acc)
{
    __shared__ __align__(16) char smem[4 * 128 * LDSPAD * 2];   // 40960 B
    __hip_bfloat16* s0 = (__hip_bfloat16*)smem;
    int blk = blockIdx.x;
    if (blk < 96) {
        dense128_body(toks_bf, dwt, dense_b, z_bf, tok_ss,
                      blk % 6, blk / 6,
                      s0, s0 + 128*LDSPAD, s0 + 2*128*LDSPAD, s0 + 3*128*LDSPAD);
    } else if (blk < 192) {
        int q = blk - 96;
        int half = q >= 48 ? 1 : 0;
        int q2 = q - 48 * half;
        gemm64_body(rh_bf, fwt, half ? relP1 : relP0, (const float*)nullptr,
                    H3_/2, half * (H3_/2), H3_, H3_, DS_, 1.0f, q2 % 6, q2 / 6,
                    s0, s0 + 64*LDSPAD, s0 + 2*64*LDSPAD, s0 + 3*64*LDSPAD);
    } else {
        cls_ce_body(rh_bf, cwt, cls_b, labels, acc, (blk - 192) * 16, (float*)smem);
    }
}

// ---------------- kernel 3: C1 (64) + C2 split-K (128) = 192 blocks ----------------
__global__ __launch_bounds__(256) void c1c2_kernel(
    const float* __restrict__ relP0, const float* __restrict__ relP1,
    const float* __restrict__ fc_b, const __hip_bfloat16* __restrict__ desc_nb,
    const __hip_bfloat16* __restrict__ z_bf, const float* __restrict__ tok_ss,
    float* __restrict__ C1, float* __restrict__ C2a, float* __restrict__ C2b)
{
    __shared__ __align__(16) char smem[4 * 64 * LDSPAD * 2 + 64 * 4 * 4];  // 21504 B
    __hip_bfloat16* s0 = (__hip_bfloat16*)smem;
    __hip_bfloat16* As0 = s0;
    __hip_bfloat16* Bs0 = s0 + 64*LDSPAD;
    __hip_bfloat16* As1 = s0 + 2*64*LDSPAD;
    __hip_bfloat16* Bs1 = s0 + 3*64*LDSPAD;
    float* rssLds = (float*)(smem + 4 * 64 * LDSPAD * 2);
    int blk = blockIdx.x;
    if (blk < 64) {
        c1_body(relP0, relP1, fc_b, desc_nb, C1, blk % 8, blk / 8,
                As0, Bs0, As1, Bs1, rssLds);
    } else {
        int q = blk - 64;
        int half = q >= 64 ? 1 : 0;
        int q2 = q - 64 * half;
        gemm64_body(z_bf, z_bf + 2*H_, half ? C2b : C2a, tok_ss, H_, half * H_,
                    4*H_, 4*H_, B_, 1.0f/TEMP_, q2 % 8, q2 / 8, As0, Bs0, As1, Bs1);
    }
}

// ---------------- kernel 4: margin (512) + cos-CE (512, sums C2 partials) + finalize ----------------
__global__ __launch_bounds__(256) void tail_kernel(
    const float* __restrict__ C1, const float* __restrict__ C2a, const float* __restrict__ C2b,
    const int* __restrict__ labels, float* __restrict__ acc,
    int* __restrict__ done, float* __restrict__ out)
{
    __shared__ float sh[4];
    int blk = blockIdx.x, t = threadIdx.x;
    if (blk < 512) {
        int i = blk;
        int li = labels[i];
        const float* row = C1 + (size_t)i * B_;
        int j0 = t, j1 = t + 256;
        float m = -INFINITY;
        if (labels[j0] != li) m = row[j0];
        if (labels[j1] != li) m = fmaxf(m, row[j1]);
        float negmax = block_reduce_max(m, sh);
        if (t == 0) {
            float neg = fmaxf(negmax, 0.0f);
            float term = neg - row[i] + GAMMA_;
            if (term > 0.0f) atomicAdd(acc + 1, term);
        }
    } else {
        int i = blk - 512;
        const float* ra = C2a + (size_t)i * B_;
        const float* rb = C2b + (size_t)i * B_;
        int j0 = t, j1 = t + 256;
        float va = ra[j0] + rb[j0];
        float vb = ra[j1] + rb[j1];
        float m = block_reduce_max(fmaxf(va, vb), sh);
        float s = expf(va - m) + expf(vb - m);
        s = block_reduce_sum(s, sh);
        if (t == 0) {
            float pos = ra[i] + rb[i];
            atomicAdd(acc + 2, (logf(s) + m - pos) * (1.0f / (float)B_));
        }
    }
    __threadfence();
    if (t == 0) {
        int prev = atomicAdd(done, 1);
        if (prev == 1023) {
            float a0 = atomicAdd(acc + 0, 0.0f);
            float a1 = atomicAdd(acc + 1, 0.0f);
            float a2 = atomicAdd(acc + 2, 0.0f);
            out[0] = a0 + (1.0f - ALPHA_) * a1 + ALPHA_ * a2;
        }
    }
}

// ---------------- launch ----------------

extern "C" void kernel_launch(void* const* d_in, const int* in_sizes, int n_in,
                              void* d_out, int out_size, void* d_ws, size_t ws_size,
                              hipStream_t stream) {
    const float* bert     = (const float*)d_in[0];
    const float* desc     = (const float*)d_in[1];
    const float* dense_w  = (const float*)d_in[2];
    const float* dense_b  = (const float*)d_in[3];
    const float* cls_w    = (const float*)d_in[4];
    const float* cls_b    = (const float*)d_in[5];
    const float* fc_w     = (const float*)d_in[6];
    const float* fc_b     = (const float*)d_in[7];
    const int*   eidx     = (const int*)d_in[8];
    const int*   labels   = (const int*)d_in[9];
    float* out = (float*)d_out;

    float* fp = (float*)d_ws;
    __hip_bfloat16* rh_bf   = (__hip_bfloat16*)fp; fp += (size_t)B_*H3_/2;
    __hip_bfloat16* toks_bf = (__hip_bfloat16*)fp; fp += (size_t)B_*4*H_/2;
    __hip_bfloat16* dwt_bf  = (__hip_bfloat16*)fp; fp += (size_t)H_*H_/2;
    __hip_bfloat16* fwt_bf  = (__hip_bfloat16*)fp; fp += (size_t)DS_*H3_/2;
    __hip_bfloat16* cwt_bf  = (__hip_bfloat16*)fp; fp += (size_t)48*H3_/2;   // padded to 48 rows
    __hip_bfloat16* desc_nb = (__hip_bfloat16*)fp; fp += (size_t)B_*DS_/2;
    __hip_bfloat16* z_bf    = (__hip_bfloat16*)fp; fp += (size_t)B_*4*H_/2;
    float* relP0    = fp; fp += (size_t)B_*DS_;
    float* relP1    = fp; fp += (size_t)B_*DS_;
    float* C1       = fp; fp += (size_t)B_*B_;
    float* C2a      = fp; fp += (size_t)B_*B_;
    float* C2b      = fp; fp += (size_t)B_*B_;
    float* tok_ss   = fp; fp += (size_t)4*B_;
    float* acc      = fp; fp += 4;
    int*   done     = (int*)fp;

    // 1. prep: gather + transposes + desc norm (+ zero tok_ss/acc/done)
    prep_kernel<<<2608, 256, 0, stream>>>(bert, eidx, dense_w, fc_w, cls_w, desc,
                                          rh_bf, toks_bf, dwt_bf, fwt_bf, cwt_bf,
                                          desc_nb, tok_ss, acc, done);

    // 2. dense (-> bf16 z + row sumsq) + fc(split-K partials) + cls_ce
    gemms_kernel<<<224, 256, 0, stream>>>(toks_bf, dwt_bf, dense_b, z_bf, tok_ss,
                                          rh_bf, fwt_bf, relP0, relP1,
                                          cwt_bf, cls_b, labels, acc);

    // 3. C1 (combine partials + in-block row norm) + C2 (norm-scaled split-K)
    c1c2_kernel<<<192, 256, 0, stream>>>(relP0, relP1, fc_b, desc_nb,
                                         z_bf, tok_ss, C1, C2a, C2b);

    // 4. margin + cos-CE + finalize (last block writes out)
    tail_kernel<<<1024, 256, 0, stream>>>(C1, C2a, C2b, labels, acc, done, out);
}